// Round 2
// baseline (97.634 us; speedup 1.0000x reference)
//
#include <hip/hip_runtime.h>
#include <hip/hip_bf16.h>
#include <math.h>

// WeightedCoxNLL on MI355X — round 2.
//
// loss = -(1/n) * sum_i cens_i * (h_i - log(S_i) + log(t_i)),  S_i > 0
//   S_i = sum over j with key_j > key_i of s_j,   s_j = t_j * exp(h_j)
//   key_i = (bits(t_i) << 14) | i   (t > 0 so float bits are order-monotone;
//                                    index tie-break == stable argsort)
//   cens_i = (t_i < 2) & event_i ;  n = sum_i cens_i
// S_i == 0 identifies exactly the lexmax element (reference's [:-1] exclusion).
//
// Hot loop: per (i,j) pair = v_cmp_lt_u64 + v_cndmask + v_add (no LDS, no
// barrier; j-side loads are wave-uniform -> scalar/L1 cached).

namespace {
constexpr int N      = 16384;
constexpr int BLK    = 256;
constexpr int R      = 4;              // i's per thread
constexpr int IB     = N / (BLK * R);  // 16 i-blocks
constexpr int CHUNKS = 32;
constexpr int CHUNK  = N / CHUNKS;     // 512 j's per block
constexpr int GRID   = IB * CHUNKS;    // 512 blocks
}

// ---- ws layout (bytes) ----
// [0,      131072)  ulong  keys[N]
// [131072, 196608)  float  sv[N]
// [196608, 262144)  float  S[N]
// [262144, 262152)  float  acc[2]   (unused scratch, kept for alignment)
// [262152, 262156)  uint   flag     (1 = event_status is byte bools)
// [262156, 262160)  uint   done_ctr

__global__ __launch_bounds__(BLK)
void cox_prep(const float* __restrict__ pred, const float* __restrict__ ytime,
              const unsigned int* __restrict__ ev_words,
              unsigned long long* __restrict__ keys, float* __restrict__ sv,
              float* __restrict__ S, unsigned int* __restrict__ flag,
              unsigned int* __restrict__ done_ctr) {
  int i = blockIdx.x * BLK + threadIdx.x;
  float t = ytime[i];
  float h = pred[i];
  keys[i] = ((unsigned long long)__float_as_uint(t) << 14) |
            (unsigned long long)i;
  sv[i] = t * expf(h);
  S[i]  = 0.f;

  if (blockIdx.x == 0) {
    // Layout detection: read first 16384 bytes (safe for bool-bytes or int32
    // words). int32 0/1 values have zero bytes at every offset %4 != 0.
    unsigned int v = 0;
    for (int k = threadIdx.x; k < N / 4; k += BLK)
      v |= ev_words[k] & 0xFFFFFF00u;
    unsigned long long any = __ballot(v != 0u);
    __shared__ unsigned int sh[BLK / 64];
    if ((threadIdx.x & 63) == 0) sh[threadIdx.x >> 6] = (any != 0ull) ? 1u : 0u;
    __syncthreads();
    if (threadIdx.x == 0) {
      *flag = sh[0] | sh[1] | sh[2] | sh[3];
      *done_ctr = 0u;
    }
  }
}

__global__ __launch_bounds__(BLK)
void cox_pair(const unsigned long long* __restrict__ keys,
              const float* __restrict__ sv, float* __restrict__ S,
              const float* __restrict__ pred, const float* __restrict__ ytime,
              const void* __restrict__ ev, const unsigned int* __restrict__ flag,
              unsigned int* __restrict__ done_ctr, float* __restrict__ out) {
  const int bi = blockIdx.x & (IB - 1);
  const int c  = blockIdx.x >> 4;            // log2(IB) == 4
  const int i0 = bi * (BLK * R) + (int)threadIdx.x;

  const unsigned long long k0 = keys[i0];
  const unsigned long long k1 = keys[i0 + BLK];
  const unsigned long long k2 = keys[i0 + 2 * BLK];
  const unsigned long long k3 = keys[i0 + 3 * BLK];

  float S0 = 0.f, S1 = 0.f, S2 = 0.f, S3 = 0.f;
  const int jb = c * CHUNK;

#pragma unroll 4
  for (int j = jb; j < jb + CHUNK; j += 2) {
    // j is wave-uniform -> these compile to scalar (or L1-hit) loads.
    unsigned long long ka = keys[j], kb = keys[j + 1];
    float sa = sv[j], sb = sv[j + 1];
    S0 += (ka > k0) ? sa : 0.f;  S0 += (kb > k0) ? sb : 0.f;
    S1 += (ka > k1) ? sa : 0.f;  S1 += (kb > k1) ? sb : 0.f;
    S2 += (ka > k2) ? sa : 0.f;  S2 += (kb > k2) ? sb : 0.f;
    S3 += (ka > k3) ? sa : 0.f;  S3 += (kb > k3) ? sb : 0.f;
  }

  atomicAdd(&S[i0],           S0);
  atomicAdd(&S[i0 + BLK],     S1);
  atomicAdd(&S[i0 + 2 * BLK], S2);
  atomicAdd(&S[i0 + 3 * BLK], S3);

  // ---- last-block fused combine ----
  __threadfence();
  __shared__ unsigned int sprev;
  if (threadIdx.x == 0) sprev = atomicAdd(done_ctr, 1u);
  __syncthreads();
  if (sprev != GRID - 1) return;

  __threadfence();
  const unsigned int flagv = *flag;
  float tsum = 0.f, nsum = 0.f;
  for (int i = threadIdx.x; i < N; i += BLK) {
    float Si = __hip_atomic_load(&S[i], __ATOMIC_RELAXED,
                                 __HIP_MEMORY_SCOPE_AGENT);
    float t = ytime[i];
    float h = pred[i];
    bool e = flagv ? (((const unsigned char*)ev)[i] != 0)
                   : (((const int*)ev)[i] != 0);
    bool cens = (t < 2.0f) & e;
    float term = (cens && (Si > 0.f)) ? (h - logf(Si) + logf(t)) : 0.f;
    tsum += term;
    nsum += cens ? 1.f : 0.f;
  }
#pragma unroll
  for (int off = 32; off > 0; off >>= 1) {
    tsum += __shfl_down(tsum, off, 64);
    nsum += __shfl_down(nsum, off, 64);
  }
  __shared__ float redT[BLK / 64], redN[BLK / 64];
  if ((threadIdx.x & 63) == 0) {
    redT[threadIdx.x >> 6] = tsum;
    redN[threadIdx.x >> 6] = nsum;
  }
  __syncthreads();
  if (threadIdx.x == 0) {
    float st = redT[0] + redT[1] + redT[2] + redT[3];
    float sn = redN[0] + redN[1] + redN[2] + redN[3];
    out[0] = -st / sn;
  }
}

extern "C" void kernel_launch(void* const* d_in, const int* in_sizes, int n_in,
                              void* d_out, int out_size, void* d_ws, size_t ws_size,
                              hipStream_t stream) {
  const float* pred  = (const float*)d_in[0];
  const float* ytime = (const float*)d_in[1];
  const void*  ev    = d_in[2];
  float* out = (float*)d_out;

  char* ws = (char*)d_ws;
  unsigned long long* keys = (unsigned long long*)ws;            // 128 KB
  float*        sv   = (float*)(ws + 131072);                    // 64 KB
  float*        S    = (float*)(ws + 196608);                    // 64 KB
  unsigned int* flag = (unsigned int*)(ws + 262152);
  unsigned int* dctr = (unsigned int*)(ws + 262156);

  cox_prep<<<N / BLK, BLK, 0, stream>>>(pred, ytime, (const unsigned int*)ev,
                                        keys, sv, S, flag, dctr);
  cox_pair<<<GRID, BLK, 0, stream>>>(keys, sv, S, pred, ytime, ev, flag,
                                     dctr, out);
}

// Round 3
// 44.488 us; speedup vs baseline: 2.1946x; 2.1946x over previous
//
#include <hip/hip_runtime.h>
#include <hip/hip_bf16.h>
#include <math.h>

// WeightedCoxNLL on MI355X — round 3: bucketed counting-sort, O(N) total work.
//
// loss = -(1/n) * sum_i cens_i * (h_i - log(S_i) + log(t_i)),  S_i > 0
//   S_i = sum over j with key_j > key_i of s_j,  s_j = t_j * exp(h_j)
//   key_i = (bits(t_i) << 14) | i   (reproduces stable argsort exactly)
//
// t ~ U[0.05,1) -> monotone bucket b(t) = floor((t-0.05)*B/0.95), ~1 elem/bucket.
// S_i = sufS[b_i] (s-sum of strictly-greater buckets)
//     + sum over same-bucket elements with key_j > key_i (avg ~1 element).
// Pipeline: memset -> prep(histogram) -> scan(1 blk) -> scatter -> final(NLL).

namespace {
constexpr int N   = 16384;
constexpr int BLK = 256;
constexpr int NB  = N / BLK;          // 64 blocks
constexpr int B   = 16384;            // buckets
constexpr float TMIN  = 0.05f;
constexpr float SCALE = (float)B / 0.95f;

// ---- ws layout (bytes) ----
constexpr size_t OFF_COUNT = 0;        // uint  count[B]        65536
constexpr size_t OFF_SUMS  = 65536;    // float sumS[B]         65536
constexpr size_t OFF_ACC   = 131072;   // float acc[2]
constexpr size_t OFF_DCTR  = 131080;   // uint  done_ctr
constexpr size_t OFF_FLAG  = 131084;   // uint  flag (1 = bool-byte layout)
constexpr size_t ZBYTES    = 131088;   // single memset covers all above
constexpr size_t OFF_SV    = 131104;   // float sv[N]           65536
constexpr size_t OFF_OFFS  = 196640;   // uint  offs[B+1]       65540
constexpr size_t OFF_OFFSW = 262208;   // uint  offsWork[B]     65536
constexpr size_t OFF_SKEY  = 327744;   // u64   sortedKey[N]    131072
constexpr size_t OFF_SS    = 458816;   // float sortedS[N]      65536
constexpr size_t OFF_SUFS  = 524352;   // float sufS[B]         65536  (end 589888)
}

__device__ __forceinline__ int bucket_of(float t) {
  int b = (int)((t - TMIN) * SCALE);   // monotone non-decreasing in t
  return min(max(b, 0), B - 1);
}
__device__ __forceinline__ unsigned long long key_of(float t, int i) {
  return ((unsigned long long)__float_as_uint(t) << 14) | (unsigned long long)i;
}

__global__ __launch_bounds__(BLK)
void cox_prep(const float* __restrict__ pred, const float* __restrict__ ytime,
              const unsigned int* __restrict__ ev_words,
              float* __restrict__ sv, unsigned int* __restrict__ count,
              float* __restrict__ sumS, unsigned int* __restrict__ flag) {
  int i = blockIdx.x * BLK + threadIdx.x;
  float t = ytime[i];
  float h = pred[i];
  float s = t * expf(h);
  sv[i] = s;
  int b = bucket_of(t);
  atomicAdd(&count[b], 1u);
  atomicAdd(&sumS[b], s);

  if (blockIdx.x == 0) {
    // event_status layout detection (validated R1/R2): int32 0/1 words have
    // zero bytes at every offset %4 != 0; bool bytes don't.
    unsigned int v = 0;
    for (int k = threadIdx.x; k < N / 4; k += BLK)
      v |= ev_words[k] & 0xFFFFFF00u;
    unsigned long long any = __ballot(v != 0u);
    __shared__ unsigned int sh[BLK / 64];
    if ((threadIdx.x & 63) == 0) sh[threadIdx.x >> 6] = (any != 0ull) ? 1u : 0u;
    __syncthreads();
    if (threadIdx.x == 0) *flag = sh[0] | sh[1] | sh[2] | sh[3];
  }
}

// One block, 256 threads; 64 buckets/thread.
__global__ __launch_bounds__(BLK)
void cox_scan(const unsigned int* __restrict__ count,
              const float* __restrict__ sumS,
              unsigned int* __restrict__ offs,
              unsigned int* __restrict__ offsWork,
              float* __restrict__ sufS) {
  const int tid  = threadIdx.x;
  const int base = tid * (B / BLK);

  unsigned int csum = 0;
  float fsum = 0.f;
#pragma unroll 8
  for (int k = 0; k < B / BLK; ++k) {
    csum += count[base + k];
    fsum += sumS[base + k];
  }

  __shared__ unsigned int sc[BLK];
  __shared__ float sf[BLK];
  sc[tid] = csum;
  sf[tid] = fsum;
  __syncthreads();
  for (int off = 1; off < BLK; off <<= 1) {
    unsigned int c = (tid >= off) ? sc[tid - off] : 0u;          // prefix
    float f = (tid + off < BLK) ? sf[tid + off] : 0.f;           // suffix
    __syncthreads();
    sc[tid] += c;
    sf[tid] += f;
    __syncthreads();
  }
  unsigned int excl = sc[tid] - csum;   // counts before my bucket range
  float sufExcl = sf[tid] - fsum;       // s-sum strictly after my range

  unsigned int o = excl;
#pragma unroll 8
  for (int k = 0; k < B / BLK; ++k) {
    offs[base + k] = o;
    offsWork[base + k] = o;
    o += count[base + k];
  }
  if (tid == BLK - 1) offs[B] = o;      // == N

  float suf = sufExcl;
  for (int k = B / BLK - 1; k >= 0; --k) {
    sufS[base + k] = suf;               // sum over buckets strictly greater
    suf += sumS[base + k];
  }
}

__global__ __launch_bounds__(BLK)
void cox_scatter(const float* __restrict__ ytime, const float* __restrict__ sv,
                 unsigned int* __restrict__ offsWork,
                 unsigned long long* __restrict__ sortedKey,
                 float* __restrict__ sortedS) {
  int i = blockIdx.x * BLK + threadIdx.x;
  float t = ytime[i];
  int b = bucket_of(t);
  unsigned int pos = atomicAdd(&offsWork[b], 1u);
  sortedKey[pos] = key_of(t, i);
  sortedS[pos]   = sv[i];
}

__global__ __launch_bounds__(BLK)
void cox_final(const float* __restrict__ pred, const float* __restrict__ ytime,
               const void* __restrict__ ev, const unsigned int* __restrict__ offs,
               const float* __restrict__ sufS,
               const unsigned long long* __restrict__ sortedKey,
               const float* __restrict__ sortedS,
               const unsigned int* __restrict__ flag, float* __restrict__ acc,
               unsigned int* __restrict__ done_ctr, float* __restrict__ out) {
  const int i = blockIdx.x * BLK + (int)threadIdx.x;
  float t = ytime[i];
  float h = pred[i];
  int b = bucket_of(t);
  unsigned long long k = key_of(t, i);

  float local = 0.f;
  unsigned int p0 = offs[b], p1 = offs[b + 1];
  for (unsigned int p = p0; p < p1; ++p)
    local += (sortedKey[p] > k) ? sortedS[p] : 0.f;

  float S = sufS[b] + local;

  bool e = (*flag) ? (((const unsigned char*)ev)[i] != 0)
                   : (((const int*)ev)[i] != 0);
  bool cens = (t < 2.0f) & e;
  float term  = (cens && (S > 0.f)) ? (h - logf(S) + logf(t)) : 0.f;
  float nterm = cens ? 1.f : 0.f;

#pragma unroll
  for (int off = 32; off > 0; off >>= 1) {
    term  += __shfl_down(term, off, 64);
    nterm += __shfl_down(nterm, off, 64);
  }
  __shared__ float redT[BLK / 64], redN[BLK / 64];
  if ((threadIdx.x & 63) == 0) {
    redT[threadIdx.x >> 6] = term;
    redN[threadIdx.x >> 6] = nterm;
  }
  __syncthreads();
  if (threadIdx.x == 0) {
    atomicAdd(&acc[0], redT[0] + redT[1] + redT[2] + redT[3]);
    atomicAdd(&acc[1], redN[0] + redN[1] + redN[2] + redN[3]);
  }

  __threadfence();
  __shared__ unsigned int sprev;
  if (threadIdx.x == 0) sprev = atomicAdd(done_ctr, 1u);
  __syncthreads();
  if (sprev != gridDim.x - 1 || threadIdx.x != 0) return;
  __threadfence();
  float s0 = __hip_atomic_load(&acc[0], __ATOMIC_RELAXED, __HIP_MEMORY_SCOPE_AGENT);
  float s1 = __hip_atomic_load(&acc[1], __ATOMIC_RELAXED, __HIP_MEMORY_SCOPE_AGENT);
  out[0] = -s0 / s1;
}

extern "C" void kernel_launch(void* const* d_in, const int* in_sizes, int n_in,
                              void* d_out, int out_size, void* d_ws, size_t ws_size,
                              hipStream_t stream) {
  const float* pred  = (const float*)d_in[0];
  const float* ytime = (const float*)d_in[1];
  const void*  ev    = d_in[2];
  float* out = (float*)d_out;

  char* ws = (char*)d_ws;
  unsigned int*       count = (unsigned int*)(ws + OFF_COUNT);
  float*              sumS  = (float*)(ws + OFF_SUMS);
  float*              acc   = (float*)(ws + OFF_ACC);
  unsigned int*       dctr  = (unsigned int*)(ws + OFF_DCTR);
  unsigned int*       flag  = (unsigned int*)(ws + OFF_FLAG);
  float*              sv    = (float*)(ws + OFF_SV);
  unsigned int*       offs  = (unsigned int*)(ws + OFF_OFFS);
  unsigned int*       offsW = (unsigned int*)(ws + OFF_OFFSW);
  unsigned long long* skey  = (unsigned long long*)(ws + OFF_SKEY);
  float*              ss    = (float*)(ws + OFF_SS);
  float*              sufS  = (float*)(ws + OFF_SUFS);

  hipMemsetAsync(ws, 0, ZBYTES, stream);
  cox_prep<<<NB, BLK, 0, stream>>>(pred, ytime, (const unsigned int*)ev,
                                   sv, count, sumS, flag);
  cox_scan<<<1, BLK, 0, stream>>>(count, sumS, offs, offsW, sufS);
  cox_scatter<<<NB, BLK, 0, stream>>>(ytime, sv, offsW, skey, ss);
  cox_final<<<NB, BLK, 0, stream>>>(pred, ytime, ev, offs, sufS,
                                    skey, ss, flag, acc, dctr, out);
}